// Round 7
// baseline (171.078 us; speedup 1.0000x reference)
//
#include <hip/hip_runtime.h>

#define RES 0.1f

constexpr int B_ = 512;
constexpr int N_ = 8192;        // points per batch
constexpr int H_ = 200;
constexpr int W_ = 200;
constexpr int MAP = H_ * W_;
constexpr long long TOTAL = (long long)B_ * N_;   // 4,194,304

constexpr int TPB  = 256;       // 4 waves
constexpr int PPT  = 8;         // points per thread -> 2048 points per block
constexpr int SUBS = 4;         // blocks per batch
constexpr int NBLK = B_ * SUBS; // 2048 blocks
constexpr int GRP  = 4;         // points gathered together (16 outstanding loads)

__global__ __launch_bounds__(TPB) void collision_gather(
    const float* __restrict__ opState,
    const float* __restrict__ envs,
    float* __restrict__ partial)
{
    const int bid = blockIdx.x;
    // XCD-locality swizzle: dispatch round-robins blocks over 8 XCDs
    // (bid & 7 -> XCD). XCD x owns maps [x*64, x*64+64); its blocks walk
    // them in dispatch order, 4 consecutive blocks (per XCD) per map.
    const int x    = bid & 7;          // XCD slot
    const int s    = bid >> 3;         // 0..255 sequence on this XCD
    const int batch = x * (B_ / 8) + (s >> 2);
    const int sub   = s & 3;

    const int tid = threadIdx.x;
    const float2* pts = (const float2*)opState + (long long)batch * N_ + sub * (N_ / SUBS);
    const float*  m   = envs + (long long)batch * MAP;

    float acc = 0.0f;

    #pragma unroll
    for (int g = 0; g < PPT / GRP; ++g) {
        // ---- load 4 points (coalesced 8 B/lane) ----
        float2 p[GRP];
        #pragma unroll
        for (int j = 0; j < GRP; ++j)
            p[j] = pts[tid + (g * GRP + j) * TPB];

        // ---- compute addresses ----
        int   base[GRP];
        float dxA[GRP], dyA[GRP];
        bool  orA[GRP];
        #pragma unroll
        for (int j = 0; j < GRP; ++j) {
            const float qx = p[j].x, qy = p[j].y;
            orA[j] = (qx < -9.9f) | (qx > 9.9f) | (qy < -9.9f) | (qy > 9.9f);

            float px = fminf(fmaxf(qx, -9.9f), 9.9f);
            float py = fminf(fmaxf(qy, -9.9f), 9.9f);

            float pmx = px - 0.5f * RES;
            float pmy = py - 0.5f * RES;

            int ix = (int)floorf((pmx + 10.0f) * 10.0f);
            int iy = (int)floorf((pmy + 10.0f) * 10.0f);

            float ipx = ((float)ix + 0.5f) * RES - 10.0f;
            float ipy = ((float)iy + 0.5f) * RES - 10.0f;

            dxA[j] = (px - ipx) * 10.0f;
            dyA[j] = (py - ipy) * 10.0f;
            base[j] = ix * W_ + iy;
        }

        // ---- issue all 16 gathers back-to-back (max MLP) ----
        float v00[GRP], v01[GRP], v10[GRP], v11[GRP];
        #pragma unroll
        for (int j = 0; j < GRP; ++j) {
            v00[j] = m[base[j]];
            v01[j] = m[base[j] + 1];
            v10[j] = m[base[j] + W_];
            v11[j] = m[base[j] + W_ + 1];
        }

        // ---- blend + accumulate ----
        #pragma unroll
        for (int j = 0; j < GRP; ++j) {
            float dx = dxA[j], dy = dyA[j];
            float vx0 = (1.0f - dx) * v00[j] + dx * v10[j];
            float vx1 = (1.0f - dx) * v01[j] + dx * v11[j];
            float v   = (1.0f - dy) * vx0 + dy * vx1;

            float dists = orA[j] ? -1.0f : v;
            float viod  = 10.0f * (0.3f - dists);
            float r     = viod > 0.0f ? viod : 0.0f;
            acc += r * r;
        }
    }

    // ---- block reduction: 4 waves ----
    #pragma unroll
    for (int off = 32; off > 0; off >>= 1)
        acc += __shfl_down(acc, off, 64);

    __shared__ float sacc[TPB / 64];
    const int lane = tid & 63;
    const int wid  = tid >> 6;
    if (lane == 0) sacc[wid] = acc;
    __syncthreads();

    if (tid == 0) {
        float s2 = 0.0f;
        #pragma unroll
        for (int w = 0; w < TPB / 64; ++w) s2 += sacc[w];
        partial[bid] = s2;
    }
}

__global__ __launch_bounds__(256) void collision_final(
    const float* __restrict__ partial,
    float* __restrict__ out)
{
    float acc = 0.0f;
    #pragma unroll
    for (int k = 0; k < NBLK / 256; ++k)
        acc += partial[threadIdx.x + k * 256];

    #pragma unroll
    for (int off = 32; off > 0; off >>= 1)
        acc += __shfl_down(acc, off, 64);

    __shared__ float sacc[4];
    const int lane = threadIdx.x & 63;
    const int wid  = threadIdx.x >> 6;
    if (lane == 0) sacc[wid] = acc;
    __syncthreads();

    if (threadIdx.x == 0) {
        float s = sacc[0] + sacc[1] + sacc[2] + sacc[3];
        out[0] = s / (float)TOTAL;
    }
}

extern "C" void kernel_launch(void* const* d_in, const int* in_sizes, int n_in,
                              void* d_out, int out_size, void* d_ws, size_t ws_size,
                              hipStream_t stream) {
    const float* opState = (const float*)d_in[0];   // (512, 8192, 2) f32
    const float* envs    = (const float*)d_in[1];   // (512, 1, 200, 200) f32
    float* out     = (float*)d_out;                 // scalar f32
    float* partial = (float*)d_ws;                  // 2048 floats of scratch

    collision_gather<<<NBLK, TPB, 0, stream>>>(opState, envs, partial);
    collision_final<<<1, 256, 0, stream>>>(partial, out);
}